// Round 10
// baseline (340.375 us; speedup 1.0000x reference)
//
#include <hip/hip_runtime.h>
#include <math.h>
#include <float.h>

// Problem constants (HierNet_55705725829422)
#define NN 50000      // nodes
#define EE 800000     // edges
#define CAP 64        // max in-degree capacity (Poisson(16): P(>=64) ~ 1e-19)

// Edge partition (two-phase CSR build, zero per-edge global atomics)
#define NB 196        // coarse buckets: dst>>8, 256 nodes each (196*256 = 50176 >= NN)
#define SPAN 256      // nodes per bucket
#define BCAP 4608     // bucket capacity: mean 4096, sigma 64 -> +8 sigma

typedef unsigned short ushort_t;
typedef short short8 __attribute__((ext_vector_type(8)));
typedef float floatx4 __attribute__((ext_vector_type(4)));

__device__ __constant__ float kAVG_LOG = 2.8332133440562162f; // log(17)

__device__ inline ushort_t f2bf(float v) {
    union { float f; unsigned u; } x; x.f = v;
    unsigned r = x.u + 0x7fffu + ((x.u >> 16) & 1u);
    return (ushort_t)(r >> 16);
}
__device__ inline float bf2f(ushort_t b) {
    union { unsigned u; float f; } x; x.u = ((unsigned)b) << 16; return x.f;
}
__device__ inline float bitsf(unsigned u) {
    union { unsigned u; float f; } x; x.u = u; return x.f;
}
__device__ inline void splitbf(float v, ushort_t& hi, ushort_t& lo) {
    hi = f2bf(v);
    lo = f2bf(v - bf2f(hi));
}

// ---------------- fused weight prep: flat, 1024-thread stride ----------------
template <int F>
__device__ void prep_ab_dev(const float* __restrict__ We, const float* __restrict__ be,
                            const float* __restrict__ Wpre, const float* __restrict__ bpre,
                            float* __restrict__ U, float* __restrict__ Wab,
                            float* __restrict__ bias_ab) {
    const int TF = 2 * F;
    int tid = threadIdx.x;
    for (int idx = tid; idx < 2 * TF; idx += 1024) {
        int c = idx / TF, f = idx % TF;
        int t = f / F, o = f % F;
        float s = 0.f;
        for (int g = 0; g < F; ++g)
            s += We[c * F + g] * Wpre[((size_t)t * 3 * F + 2 * F + g) * F + o];
        U[idx] = s;
    }
    for (int idx = tid; idx < F * 2 * TF; idx += 1024) {
        int g = idx / (2 * TF), cc = idx % (2 * TF);
        int t, o, row;
        if (cc < TF) { t = cc / F; o = cc % F; row = g; }
        else { int c2 = cc - TF; t = c2 / F; o = c2 % F; row = F + g; }
        Wab[idx] = Wpre[((size_t)t * 3 * F + row) * F + o];
    }
    for (int cc = tid; cc < 2 * TF; cc += 1024) {
        float v = 0.f;
        if (cc < TF) {
            int t = cc / F, o = cc % F;
            float s = 0.f;
            for (int g = 0; g < F; ++g)
                s += be[g] * Wpre[((size_t)t * 3 * F + 2 * F + g) * F + o];
            v = s + bpre[t * F + o];
        }
        bias_ab[cc] = v;
    }
}

template <int F>
__device__ void prep_zf_elem(int idx, const float* __restrict__ Wpost, const float* __restrict__ Wlin,
                             ushort_t* __restrict__ Bh, ushort_t* __restrict__ Bl) {
    const int KT = 9 * F;
    int jg = idx / KT, k = idx - jg * KT;
    int b = jg >> 6, j = jg & 63;
    float v = 0.f;
    if (k < F) {
        if (b == 0) {
#pragma unroll
            for (int t = 0; t < 2; ++t)
#pragma unroll
                for (int c = 0; c < 32; ++c)
                    v += Wpost[((size_t)t * 13 * F + k) * 32 + c] * Wlin[(t * 32 + c) * 64 + j];
        }
    } else {
        int r = k - F;
        int t = r / (4 * F), rr = r - t * 4 * F;
#pragma unroll
        for (int c = 0; c < 32; ++c)
            v += Wpost[((size_t)t * 13 * F + F + b * 4 * F + rr) * 32 + c] * Wlin[(t * 32 + c) * 64 + j];
    }
    ushort_t h_, l_;
    splitbf(v, h_, l_);
    Bh[(size_t)jg * KT + k] = h_;
    Bl[(size_t)jg * KT + k] = l_;
}

// merged kernel block layout (1024 threads each):
#define PARTB 196     // partition blocks (4096 edges each)
#define PZ0B  54      // 192*288/1024
#define PZ1B  108     // 192*576/1024
#define PINITB 1563   // ceil(NN*32/1024)

// Merged: edge partition (independent once gcount pre-zeroed via hipMemsetAsync)
// + weight prep + x->bf16 init, one launch.
__global__ __launch_bounds__(1024) void prep_part_init(
    const int* __restrict__ ei, const float* __restrict__ ea,
    int* __restrict__ gcount, uint2* __restrict__ part,
    const float* We0, const float* be0, const float* Wpre0, const float* bpre0,
    const float* Wpost0, const float* Wlin0, const float* bpost0, const float* blin0,
    const float* We1, const float* be1, const float* Wpre1, const float* bpre1,
    const float* Wpost1, const float* Wlin1, const float* bpost1, const float* blin1,
    float* U0, float* Wab0, float* bias_ab0, ushort_t* Bh0, ushort_t* Bl0, float* bias_zf0,
    float* U1, float* Wab1, float* bias_ab1, ushort_t* Bh1, ushort_t* Bl1, float* bias_zf1,
    const float* __restrict__ x, ushort_t* __restrict__ xb) {
    __shared__ int hist[NB];
    __shared__ int lbase[NB];
    int tid = threadIdx.x;
    int b = blockIdx.x;
    if (b < PARTB) {
        int e0 = b * 4096;
        for (int i = tid; i < NB; i += 1024) hist[i] = 0;
        __syncthreads();
        int bq[4], rnk[4];
        unsigned px[4], py[4];
#pragma unroll
        for (int q = 0; q < 4; ++q) {
            int e = e0 + q * 1024 + tid;
            bq[q] = -1;
            if (e < EE) {
                int s = ei[e];
                int d = ei[EE + e];
                float2 v = *(const float2*)(ea + 2 * e);
                bq[q] = d >> 8;
                px[q] = ((unsigned)(d & 255) << 16) | (unsigned)s;
                py[q] = ((unsigned)f2bf(v.y) << 16) | (unsigned)f2bf(v.x);
                rnk[q] = atomicAdd(&hist[bq[q]], 1);
            }
        }
        __syncthreads();
        for (int i = tid; i < NB; i += 1024)
            lbase[i] = atomicAdd(&gcount[i], hist[i]);
        __syncthreads();
#pragma unroll
        for (int q = 0; q < 4; ++q) {
            if (bq[q] >= 0) {
                int slot = lbase[bq[q]] + rnk[q];
                if (slot < BCAP)
                    part[(size_t)bq[q] * BCAP + slot] = make_uint2(px[q], py[q]);
            }
        }
        return;
    }
    b -= PARTB;
    if (b < PZ0B) {
        prep_zf_elem<32>(b * 1024 + tid, Wpost0, Wlin0, Bh0, Bl0);
    } else if (b < PZ0B + PZ1B) {
        prep_zf_elem<64>((b - PZ0B) * 1024 + tid, Wpost1, Wlin1, Bh1, Bl1);
    } else if (b == PZ0B + PZ1B) {
        prep_ab_dev<32>(We0, be0, Wpre0, bpre0, U0, Wab0, bias_ab0);
    } else if (b == PZ0B + PZ1B + 1) {
        prep_ab_dev<64>(We1, be1, Wpre1, bpre1, U1, Wab1, bias_ab1);
    } else if (b == PZ0B + PZ1B + 2) {
        for (int j = tid; j < 64; j += 1024) {
            float s0 = blin0[j], s1 = blin1[j];
#pragma unroll
            for (int t = 0; t < 2; ++t)
#pragma unroll
                for (int c = 0; c < 32; ++c) {
                    s0 += bpost0[t * 32 + c] * Wlin0[(t * 32 + c) * 64 + j];
                    s1 += bpost1[t * 32 + c] * Wlin1[(t * 32 + c) * 64 + j];
                }
            bias_zf0[j] = s0;
            bias_zf1[j] = s1;
        }
    } else {
        int i = (b - (PZ0B + PZ1B + 3)) * 1024 + tid;
        if (i < NN * 32) xb[i] = f2bf(x[i]);
    }
}

// Phase 2: one block per bucket. Compact coalesced read, placement via LDS atomics,
// dense stores into an L2-resident csr window. Writes true degree cnt[n].
__device__ void csr_fill_block(int g, const int* __restrict__ gcount,
                               const uint2* __restrict__ part,
                               int* __restrict__ cnt, uint2* __restrict__ csr) {
    __shared__ int lcnt[SPAN];
    int tid = threadIdx.x;
    lcnt[tid] = 0;
    __syncthreads();
    int total = gcount[g];
    if (total > BCAP) total = BCAP;
    size_t pbase = (size_t)g * BCAP;
    for (int i = tid; i < total; i += 256) {
        uint2 rec = part[pbase + i];
        int rel = rec.x >> 16;
        int src = rec.x & 0xffff;
        int p = atomicAdd(&lcnt[rel], 1);
        if (p < CAP) {
            int node = (g << 8) + rel;
            csr[(size_t)node * CAP + p] = make_uint2((unsigned)src, rec.y);
        }
    }
    __syncthreads();
    int node = (g << 8) + tid;
    if (node < NN) cnt[node] = lcnt[tid];
}

// fp32 GEMM tile body: [Ca | Cb] = A[MxK]@B[KxN] + bias. Columns < bstart -> fp32 Ca; >= bstart -> bf16 Cb.
__device__ void gemm_bias_block(const float* __restrict__ A, const float* __restrict__ B,
                                const float* __restrict__ bias, float* __restrict__ Ca,
                                ushort_t* __restrict__ Cb, int M, int K, int Ncols, int bstart,
                                int mb, int cb) {
    __shared__ float As[32][132];
    __shared__ float Bs[32][68];
    int m0 = mb * 128, c0 = cb * 64;
    int tid = threadIdx.x;
    int tx = tid & 15, ty = tid >> 4;
    int ms = tid >> 3, u = tid & 7;
    float acc[8][4] = {};
    for (int k0 = 0; k0 < K; k0 += 32) {
#pragma unroll
        for (int p = 0; p < 4; ++p) {
            int m = ms + 32 * p;
            int gm = m0 + m;
            float4 v = make_float4(0.f, 0.f, 0.f, 0.f);
            if (gm < M) v = *(const float4*)(A + (size_t)gm * K + k0 + u * 4);
            As[u * 4 + 0][m] = v.x; As[u * 4 + 1][m] = v.y;
            As[u * 4 + 2][m] = v.z; As[u * 4 + 3][m] = v.w;
        }
#pragma unroll
        for (int p = 0; p < 2; ++p) {
            int idx = tid + 256 * p;
            int kk = idx >> 4, q = idx & 15;
            *(float4*)&Bs[kk][q * 4] = *(const float4*)(B + (size_t)(k0 + kk) * Ncols + c0 + q * 4);
        }
        __syncthreads();
#pragma unroll 8
        for (int k = 0; k < 32; ++k) {
            float a0[8], b0[4];
            *(float4*)&a0[0] = *(const float4*)&As[k][ty * 8];
            *(float4*)&a0[4] = *(const float4*)&As[k][ty * 8 + 4];
            *(float4*)&b0[0] = *(const float4*)&Bs[k][tx * 4];
#pragma unroll
            for (int i = 0; i < 8; ++i)
#pragma unroll
                for (int j = 0; j < 4; ++j) acc[i][j] = fmaf(a0[i], b0[j], acc[i][j]);
        }
        __syncthreads();
    }
    float bj[4];
#pragma unroll
    for (int j = 0; j < 4; ++j) bj[j] = bias[c0 + tx * 4 + j];
    bool bside = (c0 >= bstart);
    int TFw = bstart;
#pragma unroll
    for (int i = 0; i < 8; ++i) {
        int gm = m0 + ty * 8 + i;
        if (gm >= M) continue;
        float v0 = acc[i][0] + bj[0], v1 = acc[i][1] + bj[1];
        float v2 = acc[i][2] + bj[2], v3 = acc[i][3] + bj[3];
        if (!bside) {
            *(float4*)(Ca + (size_t)gm * TFw + c0 + tx * 4) = make_float4(v0, v1, v2, v3);
        } else {
            ushort4 w;
            w.x = f2bf(v0); w.y = f2bf(v1); w.z = f2bf(v2); w.w = f2bf(v3);
            *(ushort4*)(Cb + (size_t)gm * TFw + (c0 - bstart) + tx * 4) = w;
        }
    }
}

// standalone GEMM (layer 1 message GEMM)
__global__ __launch_bounds__(256) void gemm_bias(const float* __restrict__ A, const float* __restrict__ B,
                                                 const float* __restrict__ bias, float* __restrict__ Ca,
                                                 ushort_t* __restrict__ Cb, int M, int K, int Ncols, int bstart) {
    gemm_bias_block(A, B, bias, Ca, Cb, M, K, Ncols, bstart, blockIdx.x, blockIdx.y);
}

// Fused: CSR phase-2 fill co-scheduled with layer-0 message GEMM (R1-proven).
__global__ __launch_bounds__(256) void csr_gemm0(
    const int* __restrict__ gcount, const uint2* __restrict__ part,
    int* __restrict__ cnt, uint2* __restrict__ csr,
    const float* __restrict__ A, const float* __restrict__ B, const float* __restrict__ bias,
    float* __restrict__ Ca, ushort_t* __restrict__ Cb) {
    int bx = blockIdx.x;
    if (bx % 5 == 0) {
        csr_fill_block(bx / 5, gcount, part, cnt, csr);  // grid 978: bx/5 <= 195 always
    } else {
        int idx = bx - 1 - bx / 5;  // bijective -> 0..781
        gemm_bias_block(A, B, bias, Ca, Cb, NN, 32, 128, 64, idx % 391, idx / 391);
    }
}

// agg for ONE node by ONE wave (R9-proven body: scalar-pipe CSR stream,
// 16-edge chunks with 16 gathers in flight, guarded tail chunk).
template <int F>
__device__ void agg_node(int n, int lane,
                         const float* __restrict__ ABa, const ushort_t* __restrict__ ABb,
                         const int* __restrict__ cnt, const uint2* __restrict__ csr,
                         const float* __restrict__ U,
                         ushort_t* agg_b, float2* sc) {
    const int TF = 2 * F;
    const int FPL = TF / 64;  // 1 (F=32) or 2 (F=64)
    n = __builtin_amdgcn_readfirstlane(n);     // force SGPR: whole edge loop uniform
    int f0 = FPL * lane;

    float base[FPL], u0[FPL], u1[FPL], sum[FPL], sq[FPL], mn[FPL], mx[FPL];
#pragma unroll
    for (int r = 0; r < FPL; ++r) {
        base[r] = ABa[(size_t)n * TF + f0 + r];
        u0[r] = U[f0 + r];
        u1[r] = U[TF + f0 + r];
        sum[r] = 0.f; sq[r] = 0.f; mn[r] = FLT_MAX; mx[r] = -FLT_MAX;
    }
    int deg = cnt[n];                          // uniform -> s_load
    int ec = deg < CAP ? deg : CAP;
    const uint2* __restrict__ p = csr + (size_t)n * CAP;

    auto body = [&](unsigned epi, unsigned wvi) {
        float ex = bitsf(epi << 16);           // SALU (uniform)
        float ey = bitsf(epi & 0xffff0000u);   // SALU (uniform)
        float v[FPL];
        if constexpr (FPL == 2) {
            v[0] = bitsf(wvi << 16);
            v[1] = bitsf(wvi & 0xffff0000u);
        } else {
            v[0] = bitsf(wvi << 16);
        }
#pragma unroll
        for (int r = 0; r < FPL; ++r) {
            float q = fmaf(ex, u0[r], fmaf(ey, u1[r], v[r]));
            sum[r] += q;
            sq[r] = fmaf(q, q, sq[r]);
            mn[r] = fminf(mn[r], q);
            mx[r] = fmaxf(mx[r], q);
        }
    };

    for (int e0 = 0; e0 < ec; e0 += 16) {
        uint4 c[8];
#pragma unroll
        for (int j = 0; j < 8; ++j) c[j] = *(const uint4*)(p + e0 + 2 * j);  // s_load_dwordx4
        unsigned sb[16], ep[16];
#pragma unroll
        for (int j = 0; j < 8; ++j) {
            sb[2 * j] = c[j].x;     ep[2 * j] = c[j].y;
            sb[2 * j + 1] = c[j].z; ep[2 * j + 1] = c[j].w;
        }
        int rem = ec - e0;                     // > 0, wave-uniform
        unsigned wv[16];
        if (rem >= 16) {                       // guard-free fast path
#pragma unroll
            for (int i = 0; i < 16; ++i) {
                const ushort_t* row = ABb + (size_t)sb[i] * TF;  // uniform base
                if constexpr (FPL == 2) wv[i] = *(const unsigned*)(row + f0);
                else wv[i] = row[f0];
            }
#pragma unroll
            for (int i = 0; i < 16; ++i) body(ep[i], wv[i]);
        } else {                               // guarded tail chunk (uniform guards)
#pragma unroll
            for (int i = 0; i < 16; ++i) {
                if (i < rem) {
                    const ushort_t* row = ABb + (size_t)sb[i] * TF;
                    if constexpr (FPL == 2) wv[i] = *(const unsigned*)(row + f0);
                    else wv[i] = row[f0];
                }
            }
#pragma unroll
            for (int i = 0; i < 16; ++i)
                if (i < rem) body(ep[i], wv[i]);
        }
    }

    float d = (float)(deg > 1 ? deg : 1);
    float inv_d = 1.f / d;
    bool has = deg > 0;
#pragma unroll
    for (int r = 0; r < FPL; ++r) {
        float mean_q = sum[r] * inv_d;
        float var = sq[r] * inv_d - mean_q * mean_q;
        float stdv = sqrtf(fmaxf(var, 0.f) + 1e-5f);
        float mean = has ? base[r] + mean_q : 0.f;
        float vmn = has ? base[r] + mn[r] : 0.f;
        float vmx = has ? base[r] + mx[r] : 0.f;
        int f = f0 + r;
        int t = f / F, o = f - t * F;
        size_t rowb = (size_t)n * (4 * TF) + (size_t)t * (4 * F);
        agg_b[rowb + o] = f2bf(mean);
        agg_b[rowb + F + o] = f2bf(vmn);
        agg_b[rowb + 2 * F + o] = f2bf(vmx);
        agg_b[rowb + 3 * F + o] = f2bf(stdv);
    }
    if (lane == 0) {
        float logd = logf(d + 1.f);
        sc[n] = make_float2(logd / kAVG_LOG, kAVG_LOG / logd);
    }
}

// FUSED aggregate + MFMA Z+final GEMM. Row-aligned dependency: zf block mb consumes
// agg of exactly rows mb*128..+127, so one 512-thread kernel does:
//  phase A: 8 waves x 16 passes, agg_node for own 128 rows -> global agg_b/sc
//  __syncthreads (vmcnt drain; same-CU L2 visibility)
//  phase B: R8-proven 512-thread zf body (reads L2-hot agg_b).
// Saves 2 launches + tails; agg VALU overlaps zf MFMA across co-resident blocks.
// Math identical to the separate kernels (bitwise-same output).
template <int F, bool POOL>
__global__ __launch_bounds__(512, 2) void aggzf(
    const float* __restrict__ ABa, const ushort_t* __restrict__ ABb,
    const int* __restrict__ cnt, const uint2* __restrict__ csr,
    const float* __restrict__ U,
    const ushort_t* __restrict__ xs_b, ushort_t* agg_b,
    const ushort_t* __restrict__ Bh, const ushort_t* __restrict__ Bl,
    const float* __restrict__ bias_zf, float2* sc,
    float* __restrict__ H, ushort_t* __restrict__ H_b,
    const int* __restrict__ batch, float* __restrict__ pool) {
    const int KT = 9 * F;
    extern __shared__ char smem[];
    ushort_t* A_s  = (ushort_t*)smem;        // [128][40] = 10.2 KB
    ushort_t* Bh_s = A_s + 128 * 40;         // [192][40] = 15.4 KB
    ushort_t* Bl_s = Bh_s + 192 * 40;        // [192][40]
    float* hbuf = (float*)smem;              // POOL alias [128][68] = 34.8 KB

    int m0 = blockIdx.x * 128;
    int tid = threadIdx.x;                   // 0..511
    int lane = tid & 63;
    int wave = tid >> 6;                     // 0..7

    // ---------------- phase A: aggregate own 128 rows ----------------
#pragma unroll 1
    for (int pss = 0; pss < 16; ++pss) {
        int n = m0 + pss * 8 + wave;         // wave-uniform
        if (n < NN)
            agg_node<F>(n, lane, ABa, ABb, cnt, csr, U, agg_b, sc);
    }
    __syncthreads();                          // agg stores drained & L2-visible

    // ---------------- phase B: zf (R8 512-thread body) ----------------
    int wr = wave >> 2;                      // row half (0..1)
    int wc = wave & 3;                       // col wave  (0..3)
    int ln = lane & 15, quad = lane >> 4;

    floatx4 acc[4][3];
#pragma unroll
    for (int i = 0; i < 4; ++i)
#pragma unroll
        for (int j = 0; j < 3; ++j) acc[i][j] = (floatx4)(0.f);

    int arow = tid >> 2, asg = tid & 3;      // A staging: 1 chunk/thread (128x4)
    int bcol[2], bsg[2];
    bool bok[2];
#pragma unroll
    for (int p = 0; p < 2; ++p) {
        int idx = tid + 512 * p;
        bok[p] = idx < 768;                  // 192 cols x 4 segs
        bcol[p] = idx >> 2;
        bsg[p] = idx & 3;
    }

    const short8 zero8 = {0, 0, 0, 0, 0, 0, 0, 0};
    short8 pa, pbh[2], pbl[2];
    {
        int c0 = asg * 8;  // always < F at k0=0
        int gm = m0 + arow;
        pa = zero8;
        if (gm < NN) pa = *(const short8*)(xs_b + (size_t)gm * F + c0);
#pragma unroll
        for (int p = 0; p < 2; ++p) {
            pbh[p] = zero8; pbl[p] = zero8;
            if (bok[p]) {
                pbh[p] = *(const short8*)(Bh + (size_t)bcol[p] * KT + bsg[p] * 8);
                pbl[p] = *(const short8*)(Bl + (size_t)bcol[p] * KT + bsg[p] * 8);
            }
        }
    }

    for (int k0 = 0; k0 < KT; k0 += 32) {
        *(short8*)&A_s[arow * 40 + asg * 8] = pa;
#pragma unroll
        for (int p = 0; p < 2; ++p) {
            if (bok[p]) {
                *(short8*)&Bh_s[bcol[p] * 40 + bsg[p] * 8] = pbh[p];
                *(short8*)&Bl_s[bcol[p] * 40 + bsg[p] * 8] = pbl[p];
            }
        }
        __syncthreads();
        short8 bh[3], bl[3];
#pragma unroll
        for (int b = 0; b < 3; ++b) {
            int col = b * 64 + wc * 16 + ln;
            bh[b] = *(short8*)&Bh_s[col * 40 + quad * 8];
            bl[b] = *(short8*)&Bl_s[col * 40 + quad * 8];
        }
        int kn = k0 + 32;
        if (kn < KT) {
            int c0 = kn + asg * 8;
            int gm = m0 + arow;
            pa = zero8;
            if (gm < NN) {
                pa = (c0 < F) ? *(const short8*)(xs_b + (size_t)gm * F + c0)
                              : *(const short8*)(agg_b + (size_t)gm * 8 * F + (c0 - F));
            }
#pragma unroll
            for (int p = 0; p < 2; ++p) {
                if (bok[p]) {
                    pbh[p] = *(const short8*)(Bh + (size_t)bcol[p] * KT + kn + bsg[p] * 8);
                    pbl[p] = *(const short8*)(Bl + (size_t)bcol[p] * KT + kn + bsg[p] * 8);
                }
            }
        }
#pragma unroll
        for (int rf = 0; rf < 4; ++rf) {
            short8 ah = *(short8*)&A_s[((wr * 4 + rf) * 16 + ln) * 40 + quad * 8];
#pragma unroll
            for (int b = 0; b < 3; ++b) {
                acc[rf][b] = __builtin_amdgcn_mfma_f32_16x16x32_bf16(ah, bh[b], acc[rf][b], 0, 0, 0);
                acc[rf][b] = __builtin_amdgcn_mfma_f32_16x16x32_bf16(ah, bl[b], acc[rf][b], 0, 0, 0);
            }
        }
        __syncthreads();
    }

    int ocol = wc * 16 + ln;
    float bcolv = bias_zf[ocol];

    if (POOL) __syncthreads();  // before hbuf alias reuse

#pragma unroll
    for (int rf = 0; rf < 4; ++rf) {
#pragma unroll
        for (int reg = 0; reg < 4; ++reg) {
            int r = (wr * 4 + rf) * 16 + quad * 4 + reg;
            int gm = m0 + r;
            float2 s = make_float2(0.f, 0.f);
            if (gm < NN) s = sc[gm];
            float y = acc[rf][0][reg] + s.x * acc[rf][1][reg] + s.y * acc[rf][2][reg] + bcolv;
            y = fmaxf(y, 0.f);
            if (POOL) {
                hbuf[r * 68 + ocol] = (gm < NN) ? y : 0.f;
            } else if (gm < NN) {
                H[(size_t)gm * 64 + ocol] = y;
                H_b[(size_t)gm * 64 + ocol] = f2bf(y);
            }
        }
    }
    if (POOL) {
        __syncthreads();
        int col = tid & 63, grp = tid >> 6;    // 8 groups x 16 rows
        float a = 0.f;
        int cur = -1;
        for (int i = 0; i < 16; ++i) {
            int r = grp * 16 + i;
            int gm = m0 + r;
            if (gm >= NN) break;
            int b = batch[gm];
            if (b != cur) {
                if (cur >= 0) atomicAdd(&pool[cur * 64 + col], a);
                cur = b; a = 0.f;
            }
            a += hbuf[r * 68 + col];
        }
        if (cur >= 0) atomicAdd(&pool[cur * 64 + col], a);
    }
}

__global__ __launch_bounds__(256) void head_kernel(const float* __restrict__ gpool, const float* __restrict__ hls,
                                                   const float* __restrict__ W1, const float* __restrict__ b1,
                                                   const float* __restrict__ W2, const float* __restrict__ b2,
                                                   const float* __restrict__ W3, const float* __restrict__ b3,
                                                   float* __restrict__ out) {
    __shared__ float gin[64][96];
    __shared__ float r1[64][64];
    __shared__ float r2[64][64];
    int tid = threadIdx.x;
    for (int idx = tid; idx < 64 * 96; idx += 256) {
        int g = idx / 96, j = idx % 96;
        gin[g][j] = (j < 64) ? gpool[g * 64 + j] : hls[g * 32 + (j - 64)];
    }
    __syncthreads();
    for (int idx = tid; idx < 64 * 64; idx += 256) {
        int g = idx / 64, j = idx % 64;
        float acc = b1[j];
        for (int k = 0; k < 96; ++k) acc = fmaf(gin[g][k], W1[k * 64 + j], acc);
        r1[g][j] = fmaxf(acc, 0.f);
    }
    __syncthreads();
    for (int idx = tid; idx < 64 * 64; idx += 256) {
        int g = idx / 64, j = idx % 64;
        float acc = b2[j];
        for (int k = 0; k < 64; ++k) acc = fmaf(r1[g][k], W2[k * 64 + j], acc);
        r2[g][j] = fmaxf(acc, 0.f);
    }
    __syncthreads();
    if (tid < 64) {
        float acc = b3[0];
        for (int k = 0; k < 64; ++k) acc = fmaf(r2[tid][k], W3[k], acc);
        out[tid] = acc;
    }
}

extern "C" void kernel_launch(void* const* d_in, const int* in_sizes, int n_in,
                              void* d_out, int out_size, void* d_ws, size_t ws_size,
                              hipStream_t stream) {
    (void)in_sizes; (void)n_in; (void)out_size; (void)ws_size;
    const float* x     = (const float*)d_in[0];
    const float* eattr = (const float*)d_in[1];
    const float* hls   = (const float*)d_in[2];
    const int*   eidx  = (const int*)d_in[3];
    const int*   batch = (const int*)d_in[4];
    const float* We[2]    = {(const float*)d_in[5],  (const float*)d_in[13]};
    const float* be[2]    = {(const float*)d_in[6],  (const float*)d_in[14]};
    const float* Wpre[2]  = {(const float*)d_in[7],  (const float*)d_in[15]};
    const float* bpre[2]  = {(const float*)d_in[8],  (const float*)d_in[16]};
    const float* Wpost[2] = {(const float*)d_in[9],  (const float*)d_in[17]};
    const float* bpost[2] = {(const float*)d_in[10], (const float*)d_in[18]};
    const float* Wlin[2]  = {(const float*)d_in[11], (const float*)d_in[19]};
    const float* blin[2]  = {(const float*)d_in[12], (const float*)d_in[20]};
    const float* W1 = (const float*)d_in[21]; const float* b1 = (const float*)d_in[22];
    const float* W2 = (const float*)d_in[23]; const float* b2 = (const float*)d_in[24];
    const float* W3 = (const float*)d_in[25]; const float* b3 = (const float*)d_in[26];
    float* out = (float*)d_out;

    char* ws = (char*)d_ws;
    size_t off = 0;
    auto carve = [&](size_t bytes) -> char* {
        char* p = ws + off;
        off = (off + bytes + 255) & ~(size_t)255;
        return p;
    };
    int*      cnt      = (int*)carve((size_t)NN * 4);
    uint2*    csr      = (uint2*)carve((size_t)NN * CAP * 8);
    float*    ABa      = (float*)carve((size_t)NN * 128 * 4);
    ushort_t* ABb      = (ushort_t*)carve((size_t)NN * 128 * 2);
    ushort_t* agg_b    = (ushort_t*)carve((size_t)NN * 512 * 2);
    float2*   sc       = (float2*)carve((size_t)NN * 8);
    ushort_t* xs_b     = (ushort_t*)carve((size_t)NN * 32 * 2);
    float*    h1       = (float*)carve((size_t)NN * 64 * 4);
    ushort_t* h1_b     = (ushort_t*)carve((size_t)NN * 64 * 2);
    float*    U0       = (float*)carve(256 * 4);
    float*    U1       = (float*)carve(256 * 4);
    float*    Wab0     = (float*)carve(16384 * 4);
    float*    Wab1     = (float*)carve(16384 * 4);
    float*    bias_ab0 = (float*)carve(256 * 4);
    float*    bias_ab1 = (float*)carve(256 * 4);
    ushort_t* Bh0      = (ushort_t*)carve((size_t)192 * 288 * 2);
    ushort_t* Bl0      = (ushort_t*)carve((size_t)192 * 288 * 2);
    ushort_t* Bh1      = (ushort_t*)carve((size_t)192 * 576 * 2);
    ushort_t* Bl1      = (ushort_t*)carve((size_t)192 * 576 * 2);
    float*    bias_zf0 = (float*)carve(64 * 4);
    float*    bias_zf1 = (float*)carve(64 * 4);
    float*    pool     = (float*)carve(64 * 64 * 4);
    int*      gcount   = (int*)carve(NB * 4);
    // part aliases agg_b: consumed by csr_gemm0 before aggzf<32> writes agg_b.
    uint2*    part     = (uint2*)agg_b;

    const int MB128 = (NN + 127) / 128;  // 391
    const int SMEM_ZF = (128 * 40 + 192 * 40 + 192 * 40) * 2;  // 40960
    const int FUSEDB = NB + MB128 * 2;   // 978 -> bx%5==0 gives exactly 196 phase2 slots
    const int MERGEDB = PARTB + PZ0B + PZ1B + 3 + PINITB;      // 1924

    // zero gcount (before partition atomics) and pool (before aggzf64 atomics)
    hipMemsetAsync(gcount, 0, NB * 4, stream);
    hipMemsetAsync(pool, 0, 64 * 64 * 4, stream);

    // merged: edge partition + weight prep + x->bf16 init (one launch)
    prep_part_init<<<MERGEDB, 1024, 0, stream>>>(
        eidx, eattr, gcount, part,
        We[0], be[0], Wpre[0], bpre[0], Wpost[0], Wlin[0], bpost[0], blin[0],
        We[1], be[1], Wpre[1], bpre[1], Wpost[1], Wlin[1], bpost[1], blin[1],
        U0, Wab0, bias_ab0, Bh0, Bl0, bias_zf0,
        U1, Wab1, bias_ab1, Bh1, Bl1, bias_zf1,
        x, xs_b);

    // ---------------- layer 0 (F=32, TF=64, KT=288) ----------------
    csr_gemm0<<<FUSEDB, 256, 0, stream>>>(gcount, part, cnt, csr, x, Wab0, bias_ab0, ABa, ABb);
    aggzf<32, false><<<MB128, 512, SMEM_ZF, stream>>>(
        ABa, ABb, cnt, csr, U0, xs_b, agg_b, Bh0, Bl0, bias_zf0, sc,
        h1, h1_b, batch, pool);

    // ---------------- layer 1 (F=64, TF=128, KT=576) ----------------
    gemm_bias<<<dim3(MB128, 4), 256, 0, stream>>>(h1, Wab1, bias_ab1, ABa, ABb, NN, 64, 256, 128);
    aggzf<64, true><<<MB128, 512, SMEM_ZF, stream>>>(
        ABa, ABb, cnt, csr, U1, h1_b, agg_b, Bh1, Bl1, bias_zf1, sc,
        nullptr, nullptr, batch, pool);

    // ---------------- head ----------------
    head_kernel<<<1, 256, 0, stream>>>(pool, hls, W1, b1, W2, b2, W3, b3, out);
}

// Round 11
// 316.087 us; speedup vs baseline: 1.0768x; 1.0768x over previous
//
#include <hip/hip_runtime.h>
#include <math.h>
#include <float.h>

// Problem constants (HierNet_55705725829422)
#define NN 50000      // nodes
#define EE 800000     // edges
#define CAP 64        // max in-degree capacity (Poisson(16): P(>=64) ~ 1e-19)

// Edge partition (two-phase CSR build, zero per-edge global atomics)
#define NB 196        // coarse buckets: dst>>8, 256 nodes each (196*256 = 50176 >= NN)
#define SPAN 256      // nodes per bucket
#define BCAP 4608     // bucket capacity: mean 4096, sigma 64 -> +8 sigma

typedef unsigned short ushort_t;
typedef short short8 __attribute__((ext_vector_type(8)));
typedef float floatx4 __attribute__((ext_vector_type(4)));

__device__ __constant__ float kAVG_LOG = 2.8332133440562162f; // log(17)

__device__ inline ushort_t f2bf(float v) {
    union { float f; unsigned u; } x; x.f = v;
    unsigned r = x.u + 0x7fffu + ((x.u >> 16) & 1u);
    return (ushort_t)(r >> 16);
}
__device__ inline float bf2f(ushort_t b) {
    union { unsigned u; float f; } x; x.u = ((unsigned)b) << 16; return x.f;
}
__device__ inline float bitsf(unsigned u) {
    union { unsigned u; float f; } x; x.u = u; return x.f;
}
__device__ inline void splitbf(float v, ushort_t& hi, ushort_t& lo) {
    hi = f2bf(v);
    lo = f2bf(v - bf2f(hi));
}

// ---------------- fused weight prep: flat, 1024-thread stride ----------------
template <int F>
__device__ void prep_ab_dev(const float* __restrict__ We, const float* __restrict__ be,
                            const float* __restrict__ Wpre, const float* __restrict__ bpre,
                            float* __restrict__ U, float* __restrict__ Wab,
                            float* __restrict__ bias_ab) {
    const int TF = 2 * F;
    int tid = threadIdx.x;
    for (int idx = tid; idx < 2 * TF; idx += 1024) {
        int c = idx / TF, f = idx % TF;
        int t = f / F, o = f % F;
        float s = 0.f;
        for (int g = 0; g < F; ++g)
            s += We[c * F + g] * Wpre[((size_t)t * 3 * F + 2 * F + g) * F + o];
        U[idx] = s;
    }
    for (int idx = tid; idx < F * 2 * TF; idx += 1024) {
        int g = idx / (2 * TF), cc = idx % (2 * TF);
        int t, o, row;
        if (cc < TF) { t = cc / F; o = cc % F; row = g; }
        else { int c2 = cc - TF; t = c2 / F; o = c2 % F; row = F + g; }
        Wab[idx] = Wpre[((size_t)t * 3 * F + row) * F + o];
    }
    for (int cc = tid; cc < 2 * TF; cc += 1024) {
        float v = 0.f;
        if (cc < TF) {
            int t = cc / F, o = cc % F;
            float s = 0.f;
            for (int g = 0; g < F; ++g)
                s += be[g] * Wpre[((size_t)t * 3 * F + 2 * F + g) * F + o];
            v = s + bpre[t * F + o];
        }
        bias_ab[cc] = v;
    }
}

template <int F>
__device__ void prep_zf_elem(int idx, const float* __restrict__ Wpost, const float* __restrict__ Wlin,
                             ushort_t* __restrict__ Bh, ushort_t* __restrict__ Bl) {
    const int KT = 9 * F;
    int jg = idx / KT, k = idx - jg * KT;
    int b = jg >> 6, j = jg & 63;
    float v = 0.f;
    if (k < F) {
        if (b == 0) {
#pragma unroll
            for (int t = 0; t < 2; ++t)
#pragma unroll
                for (int c = 0; c < 32; ++c)
                    v += Wpost[((size_t)t * 13 * F + k) * 32 + c] * Wlin[(t * 32 + c) * 64 + j];
        }
    } else {
        int r = k - F;
        int t = r / (4 * F), rr = r - t * 4 * F;
#pragma unroll
        for (int c = 0; c < 32; ++c)
            v += Wpost[((size_t)t * 13 * F + F + b * 4 * F + rr) * 32 + c] * Wlin[(t * 32 + c) * 64 + j];
    }
    ushort_t h_, l_;
    splitbf(v, h_, l_);
    Bh[(size_t)jg * KT + k] = h_;
    Bl[(size_t)jg * KT + k] = l_;
}

// merged kernel block layout (1024 threads each):
#define PARTB 196     // partition blocks (4096 edges each)
#define PZ0B  54      // 192*288/1024
#define PZ1B  108     // 192*576/1024
#define PINITB 1563   // ceil(NN*32/1024)

// Merged: edge partition (independent once gcount pre-zeroed via hipMemsetAsync)
// + weight prep + x->bf16 init, one launch (R8-proven).
__global__ __launch_bounds__(1024) void prep_part_init(
    const int* __restrict__ ei, const float* __restrict__ ea,
    int* __restrict__ gcount, uint2* __restrict__ part,
    const float* We0, const float* be0, const float* Wpre0, const float* bpre0,
    const float* Wpost0, const float* Wlin0, const float* bpost0, const float* blin0,
    const float* We1, const float* be1, const float* Wpre1, const float* bpre1,
    const float* Wpost1, const float* Wlin1, const float* bpost1, const float* blin1,
    float* U0, float* Wab0, float* bias_ab0, ushort_t* Bh0, ushort_t* Bl0, float* bias_zf0,
    float* U1, float* Wab1, float* bias_ab1, ushort_t* Bh1, ushort_t* Bl1, float* bias_zf1,
    const float* __restrict__ x, ushort_t* __restrict__ xb) {
    __shared__ int hist[NB];
    __shared__ int lbase[NB];
    int tid = threadIdx.x;
    int b = blockIdx.x;
    if (b < PARTB) {
        // ---- phase 1 partition: per-block LDS histogram + rank, 1 global atomic/(block,bucket)
        int e0 = b * 4096;
        for (int i = tid; i < NB; i += 1024) hist[i] = 0;
        __syncthreads();
        int bq[4], rnk[4];
        unsigned px[4], py[4];
#pragma unroll
        for (int q = 0; q < 4; ++q) {
            int e = e0 + q * 1024 + tid;
            bq[q] = -1;
            if (e < EE) {
                int s = ei[e];
                int d = ei[EE + e];
                float2 v = *(const float2*)(ea + 2 * e);
                bq[q] = d >> 8;
                px[q] = ((unsigned)(d & 255) << 16) | (unsigned)s;
                py[q] = ((unsigned)f2bf(v.y) << 16) | (unsigned)f2bf(v.x);
                rnk[q] = atomicAdd(&hist[bq[q]], 1);
            }
        }
        __syncthreads();
        for (int i = tid; i < NB; i += 1024)
            lbase[i] = atomicAdd(&gcount[i], hist[i]);
        __syncthreads();
#pragma unroll
        for (int q = 0; q < 4; ++q) {
            if (bq[q] >= 0) {
                int slot = lbase[bq[q]] + rnk[q];
                if (slot < BCAP)
                    part[(size_t)bq[q] * BCAP + slot] = make_uint2(px[q], py[q]);
            }
        }
        return;
    }
    b -= PARTB;
    if (b < PZ0B) {
        prep_zf_elem<32>(b * 1024 + tid, Wpost0, Wlin0, Bh0, Bl0);
    } else if (b < PZ0B + PZ1B) {
        prep_zf_elem<64>((b - PZ0B) * 1024 + tid, Wpost1, Wlin1, Bh1, Bl1);
    } else if (b == PZ0B + PZ1B) {
        prep_ab_dev<32>(We0, be0, Wpre0, bpre0, U0, Wab0, bias_ab0);
    } else if (b == PZ0B + PZ1B + 1) {
        prep_ab_dev<64>(We1, be1, Wpre1, bpre1, U1, Wab1, bias_ab1);
    } else if (b == PZ0B + PZ1B + 2) {
        for (int j = tid; j < 64; j += 1024) {
            float s0 = blin0[j], s1 = blin1[j];
#pragma unroll
            for (int t = 0; t < 2; ++t)
#pragma unroll
                for (int c = 0; c < 32; ++c) {
                    s0 += bpost0[t * 32 + c] * Wlin0[(t * 32 + c) * 64 + j];
                    s1 += bpost1[t * 32 + c] * Wlin1[(t * 32 + c) * 64 + j];
                }
            bias_zf0[j] = s0;
            bias_zf1[j] = s1;
        }
    } else {
        int i = (b - (PZ0B + PZ1B + 3)) * 1024 + tid;
        if (i < NN * 32) xb[i] = f2bf(x[i]);
    }
}

// Phase 2: one block per bucket. Compact coalesced read, placement via LDS atomics,
// dense stores into an L2-resident csr window. Writes true degree cnt[n].
__device__ void csr_fill_block(int g, const int* __restrict__ gcount,
                               const uint2* __restrict__ part,
                               int* __restrict__ cnt, uint2* __restrict__ csr) {
    __shared__ int lcnt[SPAN];
    int tid = threadIdx.x;
    lcnt[tid] = 0;
    __syncthreads();
    int total = gcount[g];
    if (total > BCAP) total = BCAP;
    size_t pbase = (size_t)g * BCAP;
    for (int i = tid; i < total; i += 256) {
        uint2 rec = part[pbase + i];
        int rel = rec.x >> 16;
        int src = rec.x & 0xffff;
        int p = atomicAdd(&lcnt[rel], 1);
        if (p < CAP) {
            int node = (g << 8) + rel;
            csr[(size_t)node * CAP + p] = make_uint2((unsigned)src, rec.y);
        }
    }
    __syncthreads();
    int node = (g << 8) + tid;
    if (node < NN) cnt[node] = lcnt[tid];
}

// fp32 GEMM tile body: [Ca | Cb] = A[MxK]@B[KxN] + bias. Columns < bstart -> fp32 Ca; >= bstart -> bf16 Cb.
__device__ void gemm_bias_block(const float* __restrict__ A, const float* __restrict__ B,
                                const float* __restrict__ bias, float* __restrict__ Ca,
                                ushort_t* __restrict__ Cb, int M, int K, int Ncols, int bstart,
                                int mb, int cb) {
    __shared__ float As[32][132];
    __shared__ float Bs[32][68];
    int m0 = mb * 128, c0 = cb * 64;
    int tid = threadIdx.x;
    int tx = tid & 15, ty = tid >> 4;
    int ms = tid >> 3, u = tid & 7;
    float acc[8][4] = {};
    for (int k0 = 0; k0 < K; k0 += 32) {
#pragma unroll
        for (int p = 0; p < 4; ++p) {
            int m = ms + 32 * p;
            int gm = m0 + m;
            float4 v = make_float4(0.f, 0.f, 0.f, 0.f);
            if (gm < M) v = *(const float4*)(A + (size_t)gm * K + k0 + u * 4);
            As[u * 4 + 0][m] = v.x; As[u * 4 + 1][m] = v.y;
            As[u * 4 + 2][m] = v.z; As[u * 4 + 3][m] = v.w;
        }
#pragma unroll
        for (int p = 0; p < 2; ++p) {
            int idx = tid + 256 * p;
            int kk = idx >> 4, q = idx & 15;
            *(float4*)&Bs[kk][q * 4] = *(const float4*)(B + (size_t)(k0 + kk) * Ncols + c0 + q * 4);
        }
        __syncthreads();
#pragma unroll 8
        for (int k = 0; k < 32; ++k) {
            float a0[8], b0[4];
            *(float4*)&a0[0] = *(const float4*)&As[k][ty * 8];
            *(float4*)&a0[4] = *(const float4*)&As[k][ty * 8 + 4];
            *(float4*)&b0[0] = *(const float4*)&Bs[k][tx * 4];
#pragma unroll
            for (int i = 0; i < 8; ++i)
#pragma unroll
                for (int j = 0; j < 4; ++j) acc[i][j] = fmaf(a0[i], b0[j], acc[i][j]);
        }
        __syncthreads();
    }
    float bj[4];
#pragma unroll
    for (int j = 0; j < 4; ++j) bj[j] = bias[c0 + tx * 4 + j];
    bool bside = (c0 >= bstart);
    int TFw = bstart;
#pragma unroll
    for (int i = 0; i < 8; ++i) {
        int gm = m0 + ty * 8 + i;
        if (gm >= M) continue;
        float v0 = acc[i][0] + bj[0], v1 = acc[i][1] + bj[1];
        float v2 = acc[i][2] + bj[2], v3 = acc[i][3] + bj[3];
        if (!bside) {
            *(float4*)(Ca + (size_t)gm * TFw + c0 + tx * 4) = make_float4(v0, v1, v2, v3);
        } else {
            ushort4 w;
            w.x = f2bf(v0); w.y = f2bf(v1); w.z = f2bf(v2); w.w = f2bf(v3);
            *(ushort4*)(Cb + (size_t)gm * TFw + (c0 - bstart) + tx * 4) = w;
        }
    }
}

// standalone GEMM (layer 1 message GEMM)
__global__ __launch_bounds__(256) void gemm_bias(const float* __restrict__ A, const float* __restrict__ B,
                                                 const float* __restrict__ bias, float* __restrict__ Ca,
                                                 ushort_t* __restrict__ Cb, int M, int K, int Ncols, int bstart) {
    gemm_bias_block(A, B, bias, Ca, Cb, M, K, Ncols, bstart, blockIdx.x, blockIdx.y);
}

// Fused: CSR phase-2 fill co-scheduled with layer-0 message GEMM (R1-proven).
__global__ __launch_bounds__(256) void csr_gemm0(
    const int* __restrict__ gcount, const uint2* __restrict__ part,
    int* __restrict__ cnt, uint2* __restrict__ csr,
    const float* __restrict__ A, const float* __restrict__ B, const float* __restrict__ bias,
    float* __restrict__ Ca, ushort_t* __restrict__ Cb) {
    int bx = blockIdx.x;
    if (bx % 5 == 0) {
        csr_fill_block(bx / 5, gcount, part, cnt, csr);  // grid 978: bx/5 <= 195 always
    } else {
        int idx = bx - 1 - bx / 5;  // bijective -> 0..781
        gemm_bias_block(A, B, bias, Ca, Cb, NN, 32, 128, 64, idx % 391, idx / 391);
    }
}

// aggregate: ONE wave per node, wave-uniform CSR stream on the SCALAR pipe.
// Wide grid (12500 blocks) -- R10 proved fusing this into the zf grid starves its TLP.
// F=64: R9-measured 16-edge guarded chunks (42.8 vs 44.5 us per-dispatch).
// F=32: R8-measured 8-batch main + serial tail (best total config).
template <int F>
__global__ __launch_bounds__(256) void aggregate(const float* __restrict__ ABa, const ushort_t* __restrict__ ABb,
                                                 const int* __restrict__ cnt, const uint2* __restrict__ csr,
                                                 const float* __restrict__ U,
                                                 ushort_t* __restrict__ agg_b, float2* __restrict__ sc) {
    const int TF = 2 * F;
    const int FPL = TF / 64;  // 1 (F=32) or 2 (F=64)
    int lane = threadIdx.x & 63;
    int n = blockIdx.x * 4 + (threadIdx.x >> 6);
    if (n >= NN) return;                       // wave-uniform exit
    n = __builtin_amdgcn_readfirstlane(n);     // force SGPR: whole edge loop uniform
    int f0 = FPL * lane;

    float base[FPL], u0[FPL], u1[FPL], sum[FPL], sq[FPL], mn[FPL], mx[FPL];
#pragma unroll
    for (int r = 0; r < FPL; ++r) {
        base[r] = ABa[(size_t)n * TF + f0 + r];
        u0[r] = U[f0 + r];
        u1[r] = U[TF + f0 + r];
        sum[r] = 0.f; sq[r] = 0.f; mn[r] = FLT_MAX; mx[r] = -FLT_MAX;
    }
    int deg = cnt[n];                          // uniform -> s_load
    int ec = deg < CAP ? deg : CAP;
    const uint2* __restrict__ p = csr + (size_t)n * CAP;

    auto body = [&](unsigned epi, unsigned wvi) {
        float ex = bitsf(epi << 16);           // SALU (uniform)
        float ey = bitsf(epi & 0xffff0000u);   // SALU (uniform)
        float v[FPL];
        if constexpr (FPL == 2) {
            v[0] = bitsf(wvi << 16);
            v[1] = bitsf(wvi & 0xffff0000u);
        } else {
            v[0] = bitsf(wvi << 16);
        }
#pragma unroll
        for (int r = 0; r < FPL; ++r) {
            float q = fmaf(ex, u0[r], fmaf(ey, u1[r], v[r]));
            sum[r] += q;
            sq[r] = fmaf(q, q, sq[r]);
            mn[r] = fminf(mn[r], q);
            mx[r] = fmaxf(mx[r], q);
        }
    };

    if constexpr (F == 64) {
        // 16-edge chunks, 16 gathers in flight, guarded tail chunk (R9-measured win).
        // Entry reads always in-bounds: e0 multiple of 16 < ec <= CAP=64.
        for (int e0 = 0; e0 < ec; e0 += 16) {
            uint4 c[8];
#pragma unroll
            for (int j = 0; j < 8; ++j) c[j] = *(const uint4*)(p + e0 + 2 * j);
            unsigned sb[16], ep[16];
#pragma unroll
            for (int j = 0; j < 8; ++j) {
                sb[2 * j] = c[j].x;     ep[2 * j] = c[j].y;
                sb[2 * j + 1] = c[j].z; ep[2 * j + 1] = c[j].w;
            }
            int rem = ec - e0;                 // > 0, wave-uniform
            unsigned wv[16];
            if (rem >= 16) {
#pragma unroll
                for (int i = 0; i < 16; ++i) {
                    const ushort_t* row = ABb + (size_t)sb[i] * TF;
                    wv[i] = *(const unsigned*)(row + f0);
                }
#pragma unroll
                for (int i = 0; i < 16; ++i) body(ep[i], wv[i]);
            } else {
#pragma unroll
                for (int i = 0; i < 16; ++i) {
                    if (i < rem) {
                        const ushort_t* row = ABb + (size_t)sb[i] * TF;
                        wv[i] = *(const unsigned*)(row + f0);
                    }
                }
#pragma unroll
                for (int i = 0; i < 16; ++i)
                    if (i < rem) body(ep[i], wv[i]);
            }
        }
    } else {
        // R8 body: 8-batch main loop + serial tail (best-total-measured for F=32).
        int e = 0;
        for (; e + 8 <= ec; e += 8) {
            uint4 c0 = *(const uint4*)(p + e);
            uint4 c1 = *(const uint4*)(p + e + 2);
            uint4 c2 = *(const uint4*)(p + e + 4);
            uint4 c3 = *(const uint4*)(p + e + 6);
            unsigned sb[8] = {c0.x, c0.z, c1.x, c1.z, c2.x, c2.z, c3.x, c3.z};
            unsigned ep[8] = {c0.y, c0.w, c1.y, c1.w, c2.y, c2.w, c3.y, c3.w};
            unsigned wv[8];
#pragma unroll
            for (int i = 0; i < 8; ++i) {
                const ushort_t* row = ABb + (size_t)sb[i] * TF;
                wv[i] = row[f0];
            }
#pragma unroll
            for (int i = 0; i < 8; ++i) body(ep[i], wv[i]);
        }
        for (; e < ec; ++e) {
            uint2 ent = p[e];
            const ushort_t* row = ABb + (size_t)ent.x * TF;
            unsigned wvt = row[f0];
            body(ent.y, wvt);
        }
    }

    float d = (float)(deg > 1 ? deg : 1);
    float inv_d = 1.f / d;
    bool has = deg > 0;
#pragma unroll
    for (int r = 0; r < FPL; ++r) {
        float mean_q = sum[r] * inv_d;
        float var = sq[r] * inv_d - mean_q * mean_q;
        float stdv = sqrtf(fmaxf(var, 0.f) + 1e-5f);
        float mean = has ? base[r] + mean_q : 0.f;
        float vmn = has ? base[r] + mn[r] : 0.f;
        float vmx = has ? base[r] + mx[r] : 0.f;
        int f = f0 + r;
        int t = f / F, o = f - t * F;
        size_t rowb = (size_t)n * (4 * TF) + (size_t)t * (4 * F);
        agg_b[rowb + o] = f2bf(mean);
        agg_b[rowb + F + o] = f2bf(vmn);
        agg_b[rowb + 2 * F + o] = f2bf(vmx);
        agg_b[rowb + 3 * F + o] = f2bf(stdv);
    }
    if (lane == 0) {
        float logd = logf(d + 1.f);
        sc[n] = make_float2(logd / kAVG_LOG, kAVG_LOG / logd);
    }
}

// MFMA merged Z+final GEMM: 128x192 tile, 512 THREADS (8 waves) -- R8-proven best.
// wave = (wr, wc); wave handles row-frags wr*4+rf (rf<4), col-frags {wc, wc+4, wc+8}.
template <int F, bool POOL>
__global__ __launch_bounds__(512, 2) void gemm_zf(
    const ushort_t* __restrict__ xs_b, const ushort_t* __restrict__ agg_b,
    const ushort_t* __restrict__ Bh, const ushort_t* __restrict__ Bl,
    const float* __restrict__ bias_zf, const float2* __restrict__ sc,
    float* __restrict__ H, ushort_t* __restrict__ H_b,
    const int* __restrict__ batch, float* __restrict__ pool) {
    const int KT = 9 * F;
    extern __shared__ char smem[];
    ushort_t* A_s  = (ushort_t*)smem;        // [128][40] = 10.2 KB
    ushort_t* Bh_s = A_s + 128 * 40;         // [192][40] = 15.4 KB
    ushort_t* Bl_s = Bh_s + 192 * 40;        // [192][40]
    float* hbuf = (float*)smem;              // POOL alias [128][68] = 34.8 KB

    int m0 = blockIdx.x * 128;
    int tid = threadIdx.x;                   // 0..511
    int lane = tid & 63;
    int wave = tid >> 6;                     // 0..7
    int wr = wave >> 2;                      // row half (0..1)
    int wc = wave & 3;                       // col wave  (0..3)
    int ln = lane & 15, quad = lane >> 4;

    floatx4 acc[4][3];
#pragma unroll
    for (int i = 0; i < 4; ++i)
#pragma unroll
        for (int j = 0; j < 3; ++j) acc[i][j] = (floatx4)(0.f);

    int arow = tid >> 2, asg = tid & 3;      // A staging: exactly 1 chunk/thread (128x4)
    int bcol[2], bsg[2];
    bool bok[2];
#pragma unroll
    for (int p = 0; p < 2; ++p) {
        int idx = tid + 512 * p;
        bok[p] = idx < 768;                  // 192 cols x 4 segs
        bcol[p] = idx >> 2;
        bsg[p] = idx & 3;
    }

    const short8 zero8 = {0, 0, 0, 0, 0, 0, 0, 0};
    short8 pa, pbh[2], pbl[2];
    {
        int c0 = asg * 8;  // always < F at k0=0
        int gm = m0 + arow;
        pa = zero8;
        if (gm < NN) pa = *(const short8*)(xs_b + (size_t)gm * F + c0);
#pragma unroll
        for (int p = 0; p < 2; ++p) {
            pbh[p] = zero8; pbl[p] = zero8;
            if (bok[p]) {
                pbh[p] = *(const short8*)(Bh + (size_t)bcol[p] * KT + bsg[p] * 8);
                pbl[p] = *(const short8*)(Bl + (size_t)bcol[p] * KT + bsg[p] * 8);
            }
        }
    }

    for (int k0 = 0; k0 < KT; k0 += 32) {
        *(short8*)&A_s[arow * 40 + asg * 8] = pa;
#pragma unroll
        for (int p = 0; p < 2; ++p) {
            if (bok[p]) {
                *(short8*)&Bh_s[bcol[p] * 40 + bsg[p] * 8] = pbh[p];
                *(short8*)&Bl_s[bcol[p] * 40 + bsg[p] * 8] = pbl[p];
            }
        }
        __syncthreads();
        short8 bh[3], bl[3];
#pragma unroll
        for (int b = 0; b < 3; ++b) {
            int col = b * 64 + wc * 16 + ln;
            bh[b] = *(short8*)&Bh_s[col * 40 + quad * 8];
            bl[b] = *(short8*)&Bl_s[col * 40 + quad * 8];
        }
        int kn = k0 + 32;
        if (kn < KT) {
            int c0 = kn + asg * 8;
            int gm = m0 + arow;
            pa = zero8;
            if (gm < NN) {
                pa = (c0 < F) ? *(const short8*)(xs_b + (size_t)gm * F + c0)
                              : *(const short8*)(agg_b + (size_t)gm * 8 * F + (c0 - F));
            }
#pragma unroll
            for (int p = 0; p < 2; ++p) {
                if (bok[p]) {
                    pbh[p] = *(const short8*)(Bh + (size_t)bcol[p] * KT + kn + bsg[p] * 8);
                    pbl[p] = *(const short8*)(Bl + (size_t)bcol[p] * KT + kn + bsg[p] * 8);
                }
            }
        }
#pragma unroll
        for (int rf = 0; rf < 4; ++rf) {
            short8 ah = *(short8*)&A_s[((wr * 4 + rf) * 16 + ln) * 40 + quad * 8];
#pragma unroll
            for (int b = 0; b < 3; ++b) {
                acc[rf][b] = __builtin_amdgcn_mfma_f32_16x16x32_bf16(ah, bh[b], acc[rf][b], 0, 0, 0);
                acc[rf][b] = __builtin_amdgcn_mfma_f32_16x16x32_bf16(ah, bl[b], acc[rf][b], 0, 0, 0);
            }
        }
        __syncthreads();
    }

    int ocol = wc * 16 + ln;
    float bcolv = bias_zf[ocol];

    if (POOL) __syncthreads();  // before hbuf alias reuse

#pragma unroll
    for (int rf = 0; rf < 4; ++rf) {
#pragma unroll
        for (int reg = 0; reg < 4; ++reg) {
            int r = (wr * 4 + rf) * 16 + quad * 4 + reg;
            int gm = m0 + r;
            float2 s = make_float2(0.f, 0.f);
            if (gm < NN) s = sc[gm];
            float y = acc[rf][0][reg] + s.x * acc[rf][1][reg] + s.y * acc[rf][2][reg] + bcolv;
            y = fmaxf(y, 0.f);
            if (POOL) {
                hbuf[r * 68 + ocol] = (gm < NN) ? y : 0.f;
            } else if (gm < NN) {
                H[(size_t)gm * 64 + ocol] = y;
                H_b[(size_t)gm * 64 + ocol] = f2bf(y);
            }
        }
    }
    if (POOL) {
        __syncthreads();
        int col = tid & 63, grp = tid >> 6;    // 8 groups x 16 rows
        float a = 0.f;
        int cur = -1;
        for (int i = 0; i < 16; ++i) {
            int r = grp * 16 + i;
            int gm = m0 + r;
            if (gm >= NN) break;
            int b = batch[gm];
            if (b != cur) {
                if (cur >= 0) atomicAdd(&pool[cur * 64 + col], a);
                cur = b; a = 0.f;
            }
            a += hbuf[r * 68 + col];
        }
        if (cur >= 0) atomicAdd(&pool[cur * 64 + col], a);
    }
}

__global__ __launch_bounds__(256) void head_kernel(const float* __restrict__ gpool, const float* __restrict__ hls,
                                                   const float* __restrict__ W1, const float* __restrict__ b1,
                                                   const float* __restrict__ W2, const float* __restrict__ b2,
                                                   const float* __restrict__ W3, const float* __restrict__ b3,
                                                   float* __restrict__ out) {
    __shared__ float gin[64][96];
    __shared__ float r1[64][64];
    __shared__ float r2[64][64];
    int tid = threadIdx.x;
    for (int idx = tid; idx < 64 * 96; idx += 256) {
        int g = idx / 96, j = idx % 96;
        gin[g][j] = (j < 64) ? gpool[g * 64 + j] : hls[g * 32 + (j - 64)];
    }
    __syncthreads();
    for (int idx = tid; idx < 64 * 64; idx += 256) {
        int g = idx / 64, j = idx % 64;
        float acc = b1[j];
        for (int k = 0; k < 96; ++k) acc = fmaf(gin[g][k], W1[k * 64 + j], acc);
        r1[g][j] = fmaxf(acc, 0.f);
    }
    __syncthreads();
    for (int idx = tid; idx < 64 * 64; idx += 256) {
        int g = idx / 64, j = idx % 64;
        float acc = b2[j];
        for (int k = 0; k < 64; ++k) acc = fmaf(r1[g][k], W2[k * 64 + j], acc);
        r2[g][j] = fmaxf(acc, 0.f);
    }
    __syncthreads();
    if (tid < 64) {
        float acc = b3[0];
        for (int k = 0; k < 64; ++k) acc = fmaf(r2[tid][k], W3[k], acc);
        out[tid] = acc;
    }
}

extern "C" void kernel_launch(void* const* d_in, const int* in_sizes, int n_in,
                              void* d_out, int out_size, void* d_ws, size_t ws_size,
                              hipStream_t stream) {
    (void)in_sizes; (void)n_in; (void)out_size; (void)ws_size;
    const float* x     = (const float*)d_in[0];
    const float* eattr = (const float*)d_in[1];
    const float* hls   = (const float*)d_in[2];
    const int*   eidx  = (const int*)d_in[3];
    const int*   batch = (const int*)d_in[4];
    const float* We[2]    = {(const float*)d_in[5],  (const float*)d_in[13]};
    const float* be[2]    = {(const float*)d_in[6],  (const float*)d_in[14]};
    const float* Wpre[2]  = {(const float*)d_in[7],  (const float*)d_in[15]};
    const float* bpre[2]  = {(const float*)d_in[8],  (const float*)d_in[16]};
    const float* Wpost[2] = {(const float*)d_in[9],  (const float*)d_in[17]};
    const float* bpost[2] = {(const float*)d_in[10], (const float*)d_in[18]};
    const float* Wlin[2]  = {(const float*)d_in[11], (const float*)d_in[19]};
    const float* blin[2]  = {(const float*)d_in[12], (const float*)d_in[20]};
    const float* W1 = (const float*)d_in[21]; const float* b1 = (const float*)d_in[22];
    const float* W2 = (const float*)d_in[23]; const float* b2 = (const float*)d_in[24];
    const float* W3 = (const float*)d_in[25]; const float* b3 = (const float*)d_in[26];
    float* out = (float*)d_out;

    char* ws = (char*)d_ws;
    size_t off = 0;
    auto carve = [&](size_t bytes) -> char* {
        char* p = ws + off;
        off = (off + bytes + 255) & ~(size_t)255;
        return p;
    };
    int*      cnt      = (int*)carve((size_t)NN * 4);
    uint2*    csr      = (uint2*)carve((size_t)NN * CAP * 8);
    float*    ABa      = (float*)carve((size_t)NN * 128 * 4);
    ushort_t* ABb      = (ushort_t*)carve((size_t)NN * 128 * 2);
    ushort_t* agg_b    = (ushort_t*)carve((size_t)NN * 512 * 2);
    float2*   sc       = (float2*)carve((size_t)NN * 8);
    ushort_t* xs_b     = (ushort_t*)carve((size_t)NN * 32 * 2);
    float*    h1       = (float*)carve((size_t)NN * 64 * 4);
    ushort_t* h1_b     = (ushort_t*)carve((size_t)NN * 64 * 2);
    float*    U0       = (float*)carve(256 * 4);
    float*    U1       = (float*)carve(256 * 4);
    float*    Wab0     = (float*)carve(16384 * 4);
    float*    Wab1     = (float*)carve(16384 * 4);
    float*    bias_ab0 = (float*)carve(256 * 4);
    float*    bias_ab1 = (float*)carve(256 * 4);
    ushort_t* Bh0      = (ushort_t*)carve((size_t)192 * 288 * 2);
    ushort_t* Bl0      = (ushort_t*)carve((size_t)192 * 288 * 2);
    ushort_t* Bh1      = (ushort_t*)carve((size_t)192 * 576 * 2);
    ushort_t* Bl1      = (ushort_t*)carve((size_t)192 * 576 * 2);
    float*    bias_zf0 = (float*)carve(64 * 4);
    float*    bias_zf1 = (float*)carve(64 * 4);
    float*    pool     = (float*)carve(64 * 64 * 4);
    int*      gcount   = (int*)carve(NB * 4);
    // part aliases agg_b: consumed by csr_gemm0 before aggregate<32> writes agg_b.
    uint2*    part     = (uint2*)agg_b;

    const int MB128 = (NN + 127) / 128;  // 391
    const int SMEM_ZF = (128 * 40 + 192 * 40 + 192 * 40) * 2;  // 40960
    const int FUSEDB = NB + MB128 * 2;   // 978 -> bx%5==0 gives exactly 196 phase2 slots
    const int MERGEDB = PARTB + PZ0B + PZ1B + 3 + PINITB;      // 1924

    // zero gcount (before partition atomics) and pool (before zf64 atomics)
    hipMemsetAsync(gcount, 0, NB * 4, stream);
    hipMemsetAsync(pool, 0, 64 * 64 * 4, stream);

    // merged: edge partition + weight prep + x->bf16 init (one launch)
    prep_part_init<<<MERGEDB, 1024, 0, stream>>>(
        eidx, eattr, gcount, part,
        We[0], be[0], Wpre[0], bpre[0], Wpost[0], Wlin[0], bpost[0], blin[0],
        We[1], be[1], Wpre[1], bpre[1], Wpost[1], Wlin[1], bpost[1], blin[1],
        U0, Wab0, bias_ab0, Bh0, Bl0, bias_zf0,
        U1, Wab1, bias_ab1, Bh1, Bl1, bias_zf1,
        x, xs_b);

    // ---------------- layer 0 (F=32, TF=64, KT=288) ----------------
    csr_gemm0<<<FUSEDB, 256, 0, stream>>>(gcount, part, cnt, csr, x, Wab0, bias_ab0, ABa, ABb);
    aggregate<32><<<(NN + 3) / 4, 256, 0, stream>>>(ABa, ABb, cnt, csr, U0, agg_b, sc);
    gemm_zf<32, false><<<MB128, 512, SMEM_ZF, stream>>>(xs_b, agg_b, Bh0, Bl0, bias_zf0, sc,
                                                        h1, h1_b, batch, pool);

    // ---------------- layer 1 (F=64, TF=128, KT=576) ----------------
    gemm_bias<<<dim3(MB128, 4), 256, 0, stream>>>(h1, Wab1, bias_ab1, ABa, ABb, NN, 64, 256, 128);
    aggregate<64><<<(NN + 3) / 4, 256, 0, stream>>>(ABa, ABb, cnt, csr, U1, agg_b, sc);
    gemm_zf<64, true><<<MB128, 512, SMEM_ZF, stream>>>(h1_b, agg_b, Bh1, Bl1, bias_zf1, sc,
                                                       nullptr, nullptr, batch, pool);

    // ---------------- head ----------------
    head_kernel<<<1, 256, 0, stream>>>(pool, hls, W1, b1, W2, b2, W3, b3, out);
}